// Round 12
// baseline (5739.090 us; speedup 1.0000x reference)
//
#include <hip/hip_runtime.h>
#include <hip/hip_bf16.h>
#include <cstdint>
#include <cstddef>

#define VOCAB  4096
#define HIDDEN 1024
#define BATCH  64
#define SEQ    256
#define NWG    32

typedef __attribute__((ext_vector_type(8))) short short8;
typedef __attribute__((ext_vector_type(4))) float f32x4;

__device__ __forceinline__ unsigned short f2bf(float f) {
    union { float f; uint32_t u; } v; v.f = f;
    uint32_t u = v.u;
    u += 0x7FFFu + ((u >> 16) & 1u);   // round-to-nearest-even
    return (unsigned short)(u >> 16);
}

// device-scope (agent) relaxed atomic store — uncached at LLC (proven r4-r11)
__device__ __forceinline__ void ast16(unsigned short* p, unsigned short v) {
    __hip_atomic_store(p, v, __ATOMIC_RELAXED, __HIP_MEMORY_SCOPE_AGENT);
}

// coherent 16B load: bypasses L1/L2 (sc0 sc1), order-pinned volatile asm (proven r7)
__device__ __forceinline__ short8 cld16(const unsigned short* p) {
    short8 v;
    asm volatile("global_load_dwordx4 %0, %1, off sc0 sc1"
                 : "=v"(v) : "v"(p) : "memory");
    return v;
}

// ---------------- zero init H + barrier flags ----------------
__global__ __launch_bounds__(256) void k_zero(float* Hf, unsigned short* Hbf, int* flags) {
    int i = blockIdx.x * 256 + threadIdx.x;
    if (i < BATCH * HIDDEN) { Hf[i] = 0.f; Hbf[i] = 0; }
    if (i < NWG * 32) flags[i] = 0;
}

// ---------------- transpose+pack: src f32 [R][C] -> dst bf16 [C][R] ----------------
__global__ __launch_bounds__(256) void k_pack(const float* __restrict__ src,
                                              unsigned short* __restrict__ dst,
                                              int R, int C) {
    __shared__ float tile[32][33];
    int tilesC = C >> 5;
    int bx = blockIdx.x % tilesC;
    int by = blockIdx.x / tilesC;
    int tx = threadIdx.x & 31;
    int ty = threadIdx.x >> 5;
    int c0 = bx << 5, r0 = by << 5;
    #pragma unroll
    for (int s = 0; s < 4; ++s) {
        int r = ty + s * 8;
        tile[r][tx] = src[(size_t)(r0 + r) * C + (c0 + tx)];
    }
    __syncthreads();
    #pragma unroll
    for (int s = 0; s < 4; ++s) {
        int cc = ty + s * 8;
        dst[(size_t)(c0 + cc) * R + (r0 + tx)] = f2bf(tile[tx][cc]);
    }
}

// ---------------- flag-tree grid barrier (relaxed flag; data via uncached ops) ----------------
__device__ __forceinline__ void flag_barrier(int* flags, int p) {
    asm volatile("s_waitcnt vmcnt(0)" ::: "memory");   // all data stores at LLC
    __syncthreads();
    if (threadIdx.x == 0)
        __hip_atomic_store(&flags[blockIdx.x * 32], p, __ATOMIC_RELAXED, __HIP_MEMORY_SCOPE_AGENT);
    if (threadIdx.x < NWG) {
        while (__hip_atomic_load(&flags[threadIdx.x * 32], __ATOMIC_RELAXED, __HIP_MEMORY_SCOPE_AGENT) < p)
            __builtin_amdgcn_s_sleep(1);
    }
    __syncthreads();
    __builtin_amdgcn_sched_barrier(0);   // rule #18: nothing hoists above the barrier
}

// ---------------- persistent GRU scan ----------------
// 32 WGs x 256 thr; WG g owns hidden cols [32g,32g+32) for z, r AND h.
// Wave w owns batch rows [16w,16w+16). Wz/Wr slices in LDS (128KB); Whh streamed (L2-hot).
__global__ __launch_bounds__(256, 1) void k_scan(
    const int* __restrict__ X,
    const float* __restrict__ Wz, const float* __restrict__ bz,
    const float* __restrict__ Wr, const float* __restrict__ br,
    const float* __restrict__ Wh, const float* __restrict__ bh,
    const unsigned short* __restrict__ Wzh, const unsigned short* __restrict__ Wrh,
    const unsigned short* __restrict__ Whh,
    float* __restrict__ Hf, unsigned short* __restrict__ Hbf,
    unsigned short* __restrict__ rHbf, unsigned short* __restrict__ Hhist,
    int* __restrict__ flags)
{
    // [cb 0..1][kk 0..31][q 0..3][row 0..15] 16B chunks (cb = col block of 16)
    __shared__ __align__(16) unsigned short WzL[32 * 1024];   // 64KB
    __shared__ __align__(16) unsigned short WrL[32 * 1024];   // 64KB

    const int tid  = threadIdx.x;
    const int g    = blockIdx.x;
    const int w    = tid >> 6;
    const int lane = tid & 63;
    const int row  = lane & 15;
    const int q    = lane >> 4;
    const int kq   = q << 3;
    const int col0 = g << 5;
    const int j0   = col0 + row;
    const int j1   = j0 + 16;
    const int b0   = w << 4;
    const int bq   = b0 + (q << 2);

    // ---- stage Wz, Wr column slices (32 cols) into LDS ----
    #pragma unroll
    for (int c = 0; c < 16; ++c) {
        int idx = tid + c * 256;            // 0..4095 16B chunks
        int cb  = idx >> 11;
        int kkg = (idx >> 6) & 31;
        int qq  = (idx >> 4) & 3;
        int rr  = idx & 15;
        size_t so = (size_t)(col0 + cb * 16 + rr) * HIDDEN + kkg * 32 + qq * 8;
        *(short8*)&WzL[idx * 8] = *(const short8*)&Wzh[so];
        *(short8*)&WrL[idx * 8] = *(const short8*)&Wrh[so];
    }
    __syncthreads();

    const float bzj0 = bz[j0], bzj1 = bz[j1];
    const float brj0 = br[j0], brj1 = br[j1];
    const float bhj0 = bh[j0], bhj1 = bh[j1];

    float zreg[2][4] = {};
    float Hreg[2][4] = {};
    int p = 0;

    // ---- prologue: tokens + embeddings for t=0 ----
    float ezc[2][4], erc[2][4], ehc[2][4];
    {
        int tk[4];
        #pragma unroll
        for (int r = 0; r < 4; ++r) tk[r] = X[(bq + r) * SEQ + 0];
        #pragma unroll
        for (int r = 0; r < 4; ++r) {
            size_t o0 = (size_t)tk[r] * HIDDEN + j0;
            size_t o1 = (size_t)tk[r] * HIDDEN + j1;
            ezc[0][r] = Wz[o0]; ezc[1][r] = Wz[o1];
            erc[0][r] = Wr[o0]; erc[1][r] = Wr[o1];
            ehc[0][r] = Wh[o0]; ehc[1][r] = Wh[o1];
        }
    }

    for (int t = 0; t < SEQ; ++t) {
        const int tn = (t + 1 < SEQ) ? t + 1 : t;
        int tokn[4];
        float ezn[2][4], ern[2][4], ehn[2][4];

        // ---------------- phase 1: z and r (LDS weights; exact vmcnt math) ----------------
        {
            const unsigned short* ap = Hbf + (size_t)(b0 + row) * HIDDEN + kq;
            short8 A[32];
            #pragma unroll
            for (int kk = 0; kk < 32; ++kk)
                A[kk] = cld16(ap + kk * 32);
            #pragma unroll
            for (int r = 0; r < 4; ++r) {
                const int* px = X + (bq + r) * SEQ + tn;
                asm volatile("global_load_dword %0, %1, off" : "=v"(tokn[r]) : "v"(px) : "memory");
            }

            f32x4 accZ0 = {0.f,0.f,0.f,0.f}, accZ1 = {0.f,0.f,0.f,0.f};
            f32x4 accR0 = {0.f,0.f,0.f,0.f}, accR1 = {0.f,0.f,0.f,0.f};
            asm volatile("s_waitcnt vmcnt(20)" ::: "memory");   // 36-20=16: A[0..15] retired
            __builtin_amdgcn_sched_barrier(0);
            #pragma unroll
            for (int kk = 0; kk < 16; ++kk) {
                int lo = kk * 512 + q * 128 + row * 8;
                short8 fz0 = *(const short8*)&WzL[lo];
                short8 fz1 = *(const short8*)&WzL[16384 + lo];
                short8 fr0 = *(const short8*)&WrL[lo];
                short8 fr1 = *(const short8*)&WrL[16384 + lo];
                accZ0 = __builtin_amdgcn_mfma_f32_16x16x32_bf16(A[kk], fz0, accZ0, 0, 0, 0);
                accZ1 = __builtin_amdgcn_mfma_f32_16x16x32_bf16(A[kk], fz1, accZ1, 0, 0, 0);
                accR0 = __builtin_amdgcn_mfma_f32_16x16x32_bf16(A[kk], fr0, accR0, 0, 0, 0);
                accR1 = __builtin_amdgcn_mfma_f32_16x16x32_bf16(A[kk], fr1, accR1, 0, 0, 0);
            }
            asm volatile("s_waitcnt vmcnt(4)" ::: "memory");    // all A retired; tokens fly
            __builtin_amdgcn_sched_barrier(0);
            #pragma unroll
            for (int kk = 16; kk < 32; ++kk) {
                int lo = kk * 512 + q * 128 + row * 8;
                short8 fz0 = *(const short8*)&WzL[lo];
                short8 fz1 = *(const short8*)&WzL[16384 + lo];
                short8 fr0 = *(const short8*)&WrL[lo];
                short8 fr1 = *(const short8*)&WrL[16384 + lo];
                accZ0 = __builtin_amdgcn_mfma_f32_16x16x32_bf16(A[kk], fz0, accZ0, 0, 0, 0);
                accZ1 = __builtin_amdgcn_mfma_f32_16x16x32_bf16(A[kk], fz1, accZ1, 0, 0, 0);
                accR0 = __builtin_amdgcn_mfma_f32_16x16x32_bf16(A[kk], fr0, accR0, 0, 0, 0);
                accR1 = __builtin_amdgcn_mfma_f32_16x16x32_bf16(A[kk], fr1, accR1, 0, 0, 0);
            }
            #pragma unroll
            for (int r = 0; r < 4; ++r) {
                float rv0 = 1.f / (1.f + expf(-(accR0[r] + erc[0][r] + brj0)));
                float rv1 = 1.f / (1.f + expf(-(accR1[r] + erc[1][r] + brj1)));
                ast16(&rHbf[(bq + r) * HIDDEN + j0], f2bf(rv0 * Hreg[0][r]));
                ast16(&rHbf[(bq + r) * HIDDEN + j1], f2bf(rv1 * Hreg[1][r]));
                zreg[0][r] = 1.f / (1.f + expf(-(accZ0[r] + ezc[0][r] + bzj0)));
                zreg[1][r] = 1.f / (1.f + expf(-(accZ1[r] + ezc[1][r] + bzj1)));
            }
        }

        flag_barrier(flags, ++p);

        // ---------------- phase 2: h + state update (Whh streamed, compiler waits) ----------------
        {
            const unsigned short* ap = rHbf + (size_t)(b0 + row) * HIDDEN + kq;
            short8 A[32];
            #pragma unroll
            for (int kk = 0; kk < 32; ++kk)
                A[kk] = cld16(ap + kk * 32);
            // 24 embedding gathers for t+1 (fly under MFMA/epilogue; drained at barrier)
            #pragma unroll
            for (int r = 0; r < 4; ++r) {
                const float* pz0 = Wz + (size_t)tokn[r] * HIDDEN + j0;
                const float* pz1 = Wz + (size_t)tokn[r] * HIDDEN + j1;
                const float* pr0 = Wr + (size_t)tokn[r] * HIDDEN + j0;
                const float* pr1 = Wr + (size_t)tokn[r] * HIDDEN + j1;
                const float* pm0 = Wh + (size_t)tokn[r] * HIDDEN + j0;
                const float* pm1 = Wh + (size_t)tokn[r] * HIDDEN + j1;
                asm volatile("global_load_dword %0, %1, off" : "=v"(ezn[0][r]) : "v"(pz0) : "memory");
                asm volatile("global_load_dword %0, %1, off" : "=v"(ezn[1][r]) : "v"(pz1) : "memory");
                asm volatile("global_load_dword %0, %1, off" : "=v"(ern[0][r]) : "v"(pr0) : "memory");
                asm volatile("global_load_dword %0, %1, off" : "=v"(ern[1][r]) : "v"(pr1) : "memory");
                asm volatile("global_load_dword %0, %1, off" : "=v"(ehn[0][r]) : "v"(pm0) : "memory");
                asm volatile("global_load_dword %0, %1, off" : "=v"(ehn[1][r]) : "v"(pm1) : "memory");
            }

            asm volatile("s_waitcnt vmcnt(24)" ::: "memory");   // 56-24=32: all A retired
            __builtin_amdgcn_sched_barrier(0);
            const unsigned short* w0 = Whh + (size_t)j0 * HIDDEN + kq;
            const unsigned short* w1 = Whh + (size_t)j1 * HIDDEN + kq;
            f32x4 acc0 = {0.f,0.f,0.f,0.f}, acc1 = {0.f,0.f,0.f,0.f};
            #pragma unroll
            for (int kk = 0; kk < 32; ++kk) {
                short8 fb0 = *(const short8*)(w0 + kk * 32);   // L2-hot cached; compiler waits
                short8 fb1 = *(const short8*)(w1 + kk * 32);
                acc0 = __builtin_amdgcn_mfma_f32_16x16x32_bf16(A[kk], fb0, acc0, 0, 0, 0);
                acc1 = __builtin_amdgcn_mfma_f32_16x16x32_bf16(A[kk], fb1, acc1, 0, 0, 0);
            }
            #pragma unroll
            for (int r = 0; r < 4; ++r) {
                int b = bq + r;
                float h0 = tanhf(acc0[r] + ehc[0][r] + bhj0);
                float h1 = tanhf(acc1[r] + ehc[1][r] + bhj1);
                float Hn0 = zreg[0][r] * h0 + (1.f - zreg[0][r]) * Hreg[0][r];
                float Hn1 = zreg[1][r] * h1 + (1.f - zreg[1][r]) * Hreg[1][r];
                Hreg[0][r] = Hn0; Hreg[1][r] = Hn1;
                unsigned short v0 = f2bf(Hn0), v1 = f2bf(Hn1);
                ast16(&Hbf[b * HIDDEN + j0], v0);
                ast16(&Hbf[b * HIDDEN + j1], v1);
                Hhist[(size_t)t * (BATCH * HIDDEN) + b * HIDDEN + j0] = v0;
                Hhist[(size_t)t * (BATCH * HIDDEN) + b * HIDDEN + j1] = v1;
                if (t == SEQ - 1) { Hf[b * HIDDEN + j0] = Hn0; Hf[b * HIDDEN + j1] = Hn1; }
            }
        }

        flag_barrier(flags, ++p);   // gathers retired inside (vmcnt(0))

        #pragma unroll
        for (int r = 0; r < 4; ++r) {
            ezc[0][r] = ezn[0][r]; ezc[1][r] = ezn[1][r];
            erc[0][r] = ern[0][r]; erc[1][r] = ern[1][r];
            ehc[0][r] = ehn[0][r]; ehc[1][r] = ehn[1][r];
        }
    }
}

// ---------------- fallback step kernels (round-1 proven) ----------------
__global__ __launch_bounds__(256) void k_step1(
    const int* __restrict__ X,
    const float* __restrict__ Wz, const float* __restrict__ bz,
    const float* __restrict__ Wr, const float* __restrict__ br,
    const unsigned short* __restrict__ Wzh, const unsigned short* __restrict__ Wrh,
    const unsigned short* __restrict__ Hbf, const float* __restrict__ Hf,
    float* __restrict__ zbuf, unsigned short* __restrict__ rHbf, int t)
{
    int w    = threadIdx.x >> 6;
    int lane = threadIdx.x & 63;
    int nt = blockIdx.x;
    int mt = w;
    bool isz = nt < 64;
    const unsigned short* W = isz ? Wzh : Wrh;
    int ntl = nt & 63;
    int row = lane & 15;
    int kq  = (lane >> 4) << 3;
    const unsigned short* aptr = Hbf + (size_t)(mt * 16 + row) * HIDDEN + kq;
    const unsigned short* bptr = W   + (size_t)(ntl * 16 + row) * HIDDEN + kq;
    f32x4 acc = {0.f, 0.f, 0.f, 0.f};
    #pragma unroll 8
    for (int kk = 0; kk < HIDDEN / 32; ++kk) {
        short8 a = *(const short8*)(aptr + kk * 32);
        short8 b = *(const short8*)(bptr + kk * 32);
        acc = __builtin_amdgcn_mfma_f32_16x16x32_bf16(a, b, acc, 0, 0, 0);
    }
    int j = ntl * 16 + row;
    const float* Wemb = isz ? Wz : Wr;
    float bias = isz ? bz[j] : br[j];
    #pragma unroll
    for (int r = 0; r < 4; ++r) {
        int b = mt * 16 + ((lane >> 4) << 2) + r;
        int tok = X[b * SEQ + t];
        float pre = acc[r] + Wemb[(size_t)tok * HIDDEN + j] + bias;
        float s = 1.f / (1.f + expf(-pre));
        if (isz) zbuf[b * HIDDEN + j] = s;
        else     rHbf[b * HIDDEN + j] = f2bf(s * Hf[b * HIDDEN + j]);
    }
}

__global__ __launch_bounds__(256) void k_step2(
    const int* __restrict__ X,
    const float* __restrict__ Wh, const float* __restrict__ bh,
    const unsigned short* __restrict__ Whh,
    const unsigned short* __restrict__ rHbf,
    const float* __restrict__ zbuf,
    float* __restrict__ Hf, unsigned short* __restrict__ Hbf,
    unsigned short* __restrict__ Hhist, int t)
{
    int w    = threadIdx.x >> 6;
    int lane = threadIdx.x & 63;
    int nt = blockIdx.x;
    int mt = w;
    int row = lane & 15;
    int kq  = (lane >> 4) << 3;
    const unsigned short* aptr = rHbf + (size_t)(mt * 16 + row) * HIDDEN + kq;
    const unsigned short* bptr = Whh  + (size_t)(nt * 16 + row) * HIDDEN + kq;
    f32x4 acc = {0.f, 0.f, 0.f, 0.f};
    #pragma unroll 8
    for (int kk = 0; kk < HIDDEN / 32; ++kk) {
        short8 a = *(const short8*)(aptr + kk * 32);
        short8 b = *(const short8*)(bptr + kk * 32);
        acc = __builtin_amdgcn_mfma_f32_16x16x32_bf16(a, b, acc, 0, 0, 0);
    }
    int j = nt * 16 + row;
    float bias = bh[j];
    #pragma unroll
    for (int r = 0; r < 4; ++r) {
        int b = mt * 16 + ((lane >> 4) << 2) + r;
        int tok = X[b * SEQ + t];
        float pre = acc[r] + Wh[(size_t)tok * HIDDEN + j] + bias;
        float h = tanhf(pre);
        float z = zbuf[b * HIDDEN + j];
        float Hold = Hf[b * HIDDEN + j];
        float Hn = z * h + (1.f - z) * Hold;
        Hf[b * HIDDEN + j] = Hn;
        unsigned short bf = f2bf(Hn);
        Hbf[b * HIDDEN + j] = bf;
        Hhist[(size_t)t * (BATCH * HIDDEN) + b * HIDDEN + j] = bf;
    }
}

// ---------------- output projection ----------------
__global__ __launch_bounds__(256) void k_out(
    const unsigned short* __restrict__ A,
    const unsigned short* __restrict__ B,
    const float* __restrict__ bo,
    float* __restrict__ out)
{
    __shared__ __align__(16) unsigned short As[128 * 32];
    __shared__ __align__(16) unsigned short Bs[128 * 32];
    int bn = blockIdx.x & 31;
    int bm = blockIdx.x >> 5;
    int m0 = bm << 7, n0 = bn << 7;
    int tid  = threadIdx.x;
    int w    = tid >> 6, lane = tid & 63;
    int wm = w & 1, wn = w >> 1;
    int row = lane & 15;
    int kq  = (lane >> 4) << 3;

    f32x4 acc[4][4];
    #pragma unroll
    for (int i = 0; i < 4; ++i)
        #pragma unroll
        for (int jj = 0; jj < 4; ++jj)
            acc[i][jj] = (f32x4){0.f, 0.f, 0.f, 0.f};

    for (int k0 = 0; k0 < HIDDEN; k0 += 32) {
        #pragma unroll
        for (int c = 0; c < 2; ++c) {
            int off  = tid * 32 + c * 16;
            int rowi = off >> 6;
            int us   = (off & 63) >> 1;
            *(short8*)&As[rowi * 32 + us] =
                *(const short8*)&A[(size_t)(m0 + rowi) * HIDDEN + k0 + us];
            *(short8*)&Bs[rowi * 32 + us] =
                *(const short8*)&B[(size_t)(n0 + rowi) * HIDDEN + k0 + us];
        }
        __syncthreads();
        short8 a[4], b[4];
        #pragma unroll
        for (int i = 0; i < 4; ++i)
            a[i] = *(const short8*)&As[(wm * 64 + i * 16 + row) * 32 + kq];
        #pragma unroll
        for (int jj = 0; jj < 4; ++jj)
            b[jj] = *(const short8*)&Bs[(wn * 64 + jj * 16 + row) * 32 + kq];
        #pragma unroll
        for (int i = 0; i < 4; ++i)
            #pragma unroll
            for (int jj = 0; jj < 4; ++jj)
                acc[i][jj] = __builtin_amdgcn_mfma_f32_16x16x32_bf16(a[i], b[jj], acc[i][jj], 0, 0, 0);
        __syncthreads();
    }

    #pragma unroll
    for (int i = 0; i < 4; ++i) {
        #pragma unroll
        for (int jj = 0; jj < 4; ++jj) {
            int n = n0 + wn * 64 + jj * 16 + row;
            float bb = bo[n];
            #pragma unroll
            for (int r = 0; r < 4; ++r) {
                int m = m0 + wm * 64 + i * 16 + ((lane >> 4) << 2) + r;
                out[(size_t)m * VOCAB + n] = acc[i][jj][r] + bb;
            }
        }
    }
}

// ---------------- H_final copy ----------------
__global__ __launch_bounds__(256) void k_copyH(const float* __restrict__ Hf,
                                               float* __restrict__ out) {
    int i = blockIdx.x * 256 + threadIdx.x;
    if (i < BATCH * HIDDEN)
        out[(size_t)SEQ * BATCH * VOCAB + i] = Hf[i];
}

extern "C" void kernel_launch(void* const* d_in, const int* in_sizes, int n_in,
                              void* d_out, int out_size, void* d_ws, size_t ws_size,
                              hipStream_t stream) {
    const int*   X  = (const int*)  d_in[0];
    const float* Wz = (const float*)d_in[1];
    const float* bz = (const float*)d_in[2];
    const float* Wr = (const float*)d_in[3];
    const float* br = (const float*)d_in[4];
    const float* Wh = (const float*)d_in[5];
    const float* bh = (const float*)d_in[6];
    const float* Wo = (const float*)d_in[7];
    const float* bo = (const float*)d_in[8];
    float* out = (float*)d_out;
    char* ws = (char*)d_ws;

    float*          Hf    = (float*)(ws);                           // 256KB
    float*          zbuf  = (float*)(ws + (256 << 10));             // 256KB (fallback only)
    int*            flags = (int*)(ws + (512 << 10));               // 8KB
    unsigned short* Hbf   = (unsigned short*)(ws + (528 << 10));    // 128KB
    unsigned short* rHbf  = (unsigned short*)(ws + (656 << 10));    // 128KB
    unsigned short* Wzh   = (unsigned short*)(ws + (1 << 20));      // 2MB
    unsigned short* Wrh   = Wzh + 1024 * 1024;                      // 2MB
    unsigned short* Whh   = Wrh + 1024 * 1024;                      // 2MB
    unsigned short* WoT   = Whh + 1024 * 1024;                      // 8MB
    unsigned short* Hhist = WoT + (size_t)VOCAB * HIDDEN;           // 32MB

    k_zero<<<256, 256, 0, stream>>>(Hf, Hbf, flags);
    k_pack<<<32 * 32,  256, 0, stream>>>(Wz + (size_t)VOCAB * HIDDEN, Wzh, 1024, 1024);
    k_pack<<<32 * 32,  256, 0, stream>>>(Wr + (size_t)VOCAB * HIDDEN, Wrh, 1024, 1024);
    k_pack<<<32 * 32,  256, 0, stream>>>(Wh + (size_t)VOCAB * HIDDEN, Whh, 1024, 1024);
    k_pack<<<32 * 128, 256, 0, stream>>>(Wo, WoT, 1024, 4096);

    void* args[] = {
        (void*)&X, (void*)&Wz, (void*)&bz, (void*)&Wr, (void*)&br,
        (void*)&Wh, (void*)&bh, (void*)&Wzh, (void*)&Wrh, (void*)&Whh,
        (void*)&Hf, (void*)&Hbf, (void*)&rHbf, (void*)&Hhist, (void*)&flags
    };
    hipError_t cerr = hipLaunchCooperativeKernel((void*)k_scan, dim3(NWG), dim3(256),
                                                 args, 0, stream);
    if (cerr != hipSuccess) {
        for (int t = 0; t < SEQ; ++t) {
            k_step1<<<128, 256, 0, stream>>>(X, Wz, bz, Wr, br, Wzh, Wrh, Hbf, Hf, zbuf, rHbf, t);
            k_step2<<<64,  256, 0, stream>>>(X, Wh, bh, Whh, rHbf, zbuf, Hf, Hbf, Hhist, t);
        }
    }

    k_out<<<4096, 256, 0, stream>>>(Hhist, WoT, bo, out);
    k_copyH<<<256, 256, 0, stream>>>(Hf, out);
}

// Round 13
// 3558.483 us; speedup vs baseline: 1.6128x; 1.6128x over previous
//
#include <hip/hip_runtime.h>
#include <hip/hip_bf16.h>
#include <cstdint>
#include <cstddef>

#define VOCAB  4096
#define HIDDEN 1024
#define BATCH  64
#define SEQ    256
#define NWG    256      // 64 col-groups x 4 batch-groups

typedef __attribute__((ext_vector_type(8))) short short8;
typedef __attribute__((ext_vector_type(4))) float f32x4;

__device__ __forceinline__ unsigned short f2bf(float f) {
    union { float f; uint32_t u; } v; v.f = f;
    uint32_t u = v.u;
    u += 0x7FFFu + ((u >> 16) & 1u);   // round-to-nearest-even
    return (unsigned short)(u >> 16);
}

// device-scope (agent) relaxed atomic store — uncached at LLC (proven r4-r12)
__device__ __forceinline__ void ast16(unsigned short* p, unsigned short v) {
    __hip_atomic_store(p, v, __ATOMIC_RELAXED, __HIP_MEMORY_SCOPE_AGENT);
}

// coherent 16B load: bypasses L1/L2 (sc0 sc1), order-pinned volatile asm (proven r7)
__device__ __forceinline__ short8 cld16(const unsigned short* p) {
    short8 v;
    asm volatile("global_load_dwordx4 %0, %1, off sc0 sc1"
                 : "=v"(v) : "v"(p) : "memory");
    return v;
}

// ---------------- zero init H + barrier flags ----------------
__global__ __launch_bounds__(256) void k_zero(float* Hf, unsigned short* Hbf, int* flags) {
    int i = blockIdx.x * 256 + threadIdx.x;
    if (i < BATCH * HIDDEN) { Hf[i] = 0.f; Hbf[i] = 0; }
    if (i < 2048) flags[i] = 0;
}

// ---------------- transpose+pack: src f32 [R][C] -> dst bf16 [C][R] ----------------
__global__ __launch_bounds__(256) void k_pack(const float* __restrict__ src,
                                              unsigned short* __restrict__ dst,
                                              int R, int C) {
    __shared__ float tile[32][33];
    int tilesC = C >> 5;
    int bx = blockIdx.x % tilesC;
    int by = blockIdx.x / tilesC;
    int tx = threadIdx.x & 31;
    int ty = threadIdx.x >> 5;
    int c0 = bx << 5, r0 = by << 5;
    #pragma unroll
    for (int s = 0; s < 4; ++s) {
        int r = ty + s * 8;
        tile[r][tx] = src[(size_t)(r0 + r) * C + (c0 + tx)];
    }
    __syncthreads();
    #pragma unroll
    for (int s = 0; s < 4; ++s) {
        int cc = ty + s * 8;
        dst[(size_t)(c0 + cc) * R + (r0 + tx)] = f2bf(tile[tx][cc]);
    }
}

// ---------------- grid barrier: 256 dense 4B flags, wave-0 polls 4/lane ----------------
__device__ __forceinline__ void flag_barrier(int* flags, int p) {
    asm volatile("s_waitcnt vmcnt(0)" ::: "memory");   // all data stores at LLC
    __syncthreads();
    if (threadIdx.x == 0)
        __hip_atomic_store(&flags[blockIdx.x], p, __ATOMIC_RELAXED, __HIP_MEMORY_SCOPE_AGENT);
    if (threadIdx.x < 64) {
        int l = threadIdx.x;
        for (;;) {
            int a = __hip_atomic_load(&flags[l],       __ATOMIC_RELAXED, __HIP_MEMORY_SCOPE_AGENT);
            int b = __hip_atomic_load(&flags[64 + l],  __ATOMIC_RELAXED, __HIP_MEMORY_SCOPE_AGENT);
            int c = __hip_atomic_load(&flags[128 + l], __ATOMIC_RELAXED, __HIP_MEMORY_SCOPE_AGENT);
            int d = __hip_atomic_load(&flags[192 + l], __ATOMIC_RELAXED, __HIP_MEMORY_SCOPE_AGENT);
            if (a >= p && b >= p && c >= p && d >= p) break;
            __builtin_amdgcn_s_sleep(1);
        }
    }
    __syncthreads();
    __builtin_amdgcn_sched_barrier(0);   // rule #18
}

// ---------------- persistent GRU scan ----------------
// 256 WGs: WG (bg,cg) owns batch rows [16bg,16bg+16) x cols [16cg,16cg+16).
// 4 waves split K (8 MFMA-slices each); cross-wave reduce in LDS.
// Weights (3 gates x 16 cols) in LDS (96KB). Exchange via uncached LLC ops.
__global__ __launch_bounds__(256, 1) void k_scan(
    const int* __restrict__ X,
    const float* __restrict__ Wz, const float* __restrict__ bz,
    const float* __restrict__ Wr, const float* __restrict__ br,
    const float* __restrict__ Wh, const float* __restrict__ bh,
    const unsigned short* __restrict__ Wzh, const unsigned short* __restrict__ Wrh,
    const unsigned short* __restrict__ Whh,
    float* __restrict__ Hf, unsigned short* __restrict__ Hbf,
    unsigned short* __restrict__ rHbf, unsigned short* __restrict__ Hhist,
    int* __restrict__ flags)
{
    __shared__ __align__(16) unsigned short WzL[16 * 1024];   // 32KB
    __shared__ __align__(16) unsigned short WrL[16 * 1024];   // 32KB
    __shared__ __align__(16) unsigned short WhL[16 * 1024];   // 32KB
    __shared__ __align__(16) f32x4 redZ[4][64];               // 4KB
    __shared__ __align__(16) f32x4 redR[4][64];               // 4KB

    const int tid  = threadIdx.x;
    const int g    = blockIdx.x;
    const int w    = tid >> 6;
    const int lane = tid & 63;
    const int row  = lane & 15;
    const int q    = lane >> 4;
    const int kq   = q << 3;
    const int cg   = g & 63;
    const int bg   = g >> 6;
    const int col0 = cg << 4;
    const int b0   = bg << 4;
    const int j    = col0 + row;
    const int bq   = b0 + (q << 2);

    // ---- stage weight slices (16 cols x 3 gates) into LDS ----
    #pragma unroll
    for (int c = 0; c < 8; ++c) {
        int idx = tid + c * 256;          // 0..2047 16B chunks
        int kkg = idx >> 6;
        int rem = idx & 63;
        int qq  = rem >> 4;
        int rr  = rem & 15;
        size_t so = (size_t)(col0 + rr) * HIDDEN + kkg * 32 + qq * 8;
        *(short8*)&WzL[idx * 8] = *(const short8*)&Wzh[so];
        *(short8*)&WrL[idx * 8] = *(const short8*)&Wrh[so];
        *(short8*)&WhL[idx * 8] = *(const short8*)&Whh[so];
    }
    __syncthreads();

    const float bzj = bz[j], brj = br[j], bhj = bh[j];

    float zreg[4] = {0.f, 0.f, 0.f, 0.f};
    float Hreg[4] = {0.f, 0.f, 0.f, 0.f};
    int p = 0;

    // ---- prologue: tokens + embeddings for t=0 ----
    float ezc[4], erc[4], ehc[4];
    {
        int tk[4];
        #pragma unroll
        for (int r = 0; r < 4; ++r) tk[r] = X[(bq + r) * SEQ + 0];
        #pragma unroll
        for (int r = 0; r < 4; ++r) {
            ezc[r] = Wz[(size_t)tk[r] * HIDDEN + j];
            erc[r] = Wr[(size_t)tk[r] * HIDDEN + j];
            ehc[r] = Wh[(size_t)tk[r] * HIDDEN + j];
        }
    }

    for (int t = 0; t < SEQ; ++t) {
        const int tn = (t + 1 < SEQ) ? t + 1 : t;
        int tokn[4];
        float ezn[4], ern[4], ehn[4];

        // ---------------- phase 1: z and r ----------------
        {
            const unsigned short* ap = Hbf + (size_t)(b0 + row) * HIDDEN + kq;
            short8 A[8];
            #pragma unroll
            for (int kkL = 0; kkL < 8; ++kkL)
                A[kkL] = cld16(ap + (w * 8 + kkL) * 32);
            #pragma unroll
            for (int r = 0; r < 4; ++r) {
                const int* px = X + (bq + r) * SEQ + tn;
                asm volatile("global_load_dword %0, %1, off" : "=v"(tokn[r]) : "v"(px) : "memory");
            }

            f32x4 aZ = {0.f,0.f,0.f,0.f}, aR = {0.f,0.f,0.f,0.f};
            asm volatile("s_waitcnt vmcnt(4)" ::: "memory");   // 12-4=8: all A retired
            __builtin_amdgcn_sched_barrier(0);
            #pragma unroll
            for (int kkL = 0; kkL < 8; ++kkL) {
                int lo = (w * 8 + kkL) * 512 + q * 128 + row * 8;
                short8 fz = *(const short8*)&WzL[lo];
                short8 fr = *(const short8*)&WrL[lo];
                aZ = __builtin_amdgcn_mfma_f32_16x16x32_bf16(A[kkL], fz, aZ, 0, 0, 0);
                aR = __builtin_amdgcn_mfma_f32_16x16x32_bf16(A[kkL], fr, aR, 0, 0, 0);
            }
            redZ[w][lane] = aZ;
            redR[w][lane] = aR;
            __syncthreads();
            f32x4 sZ = redZ[0][lane]; f32x4 sR = redR[0][lane];
            #pragma unroll
            for (int ww = 1; ww < 4; ++ww) { sZ += redZ[ww][lane]; sR += redR[ww][lane]; }

            #pragma unroll
            for (int r = 0; r < 4; ++r) {
                float rv = 1.f / (1.f + expf(-(sR[r] + erc[r] + brj)));
                zreg[r]  = 1.f / (1.f + expf(-(sZ[r] + ezc[r] + bzj)));
                if (w == 0)
                    ast16(&rHbf[(bq + r) * HIDDEN + j], f2bf(rv * Hreg[r]));
            }
        }

        flag_barrier(flags, ++p);

        // ---------------- phase 2: h + state update ----------------
        {
            const unsigned short* ap = rHbf + (size_t)(b0 + row) * HIDDEN + kq;
            short8 A[8];
            #pragma unroll
            for (int kkL = 0; kkL < 8; ++kkL)
                A[kkL] = cld16(ap + (w * 8 + kkL) * 32);
            // 12 embedding gathers for t+1 (fly under reduce/epilogue; drained at barrier)
            #pragma unroll
            for (int r = 0; r < 4; ++r) {
                const float* pz = Wz + (size_t)tokn[r] * HIDDEN + j;
                const float* pr = Wr + (size_t)tokn[r] * HIDDEN + j;
                const float* pm = Wh + (size_t)tokn[r] * HIDDEN + j;
                asm volatile("global_load_dword %0, %1, off" : "=v"(ezn[r]) : "v"(pz) : "memory");
                asm volatile("global_load_dword %0, %1, off" : "=v"(ern[r]) : "v"(pr) : "memory");
                asm volatile("global_load_dword %0, %1, off" : "=v"(ehn[r]) : "v"(pm) : "memory");
            }

            f32x4 aH = {0.f,0.f,0.f,0.f};
            asm volatile("s_waitcnt vmcnt(12)" ::: "memory");  // 20-12=8: all A retired
            __builtin_amdgcn_sched_barrier(0);
            #pragma unroll
            for (int kkL = 0; kkL < 8; ++kkL) {
                int lo = (w * 8 + kkL) * 512 + q * 128 + row * 8;
                short8 fh = *(const short8*)&WhL[lo];
                aH = __builtin_amdgcn_mfma_f32_16x16x32_bf16(A[kkL], fh, aH, 0, 0, 0);
            }
            redZ[w][lane] = aH;      // reuse (prev reads fenced by flag_barrier's syncthreads)
            __syncthreads();
            f32x4 sH = redZ[0][lane];
            #pragma unroll
            for (int ww = 1; ww < 4; ++ww) sH += redZ[ww][lane];

            #pragma unroll
            for (int r = 0; r < 4; ++r) {
                int b = bq + r;
                float h  = tanhf(sH[r] + ehc[r] + bhj);
                float Hn = zreg[r] * h + (1.f - zreg[r]) * Hreg[r];
                Hreg[r] = Hn;
                if (w == 0) {
                    unsigned short bfv = f2bf(Hn);
                    ast16(&Hbf[b * HIDDEN + j], bfv);
                    Hhist[(size_t)t * (BATCH * HIDDEN) + b * HIDDEN + j] = bfv;
                    if (t == SEQ - 1) Hf[b * HIDDEN + j] = Hn;
                }
            }
        }

        flag_barrier(flags, ++p);   // gathers retired inside (vmcnt(0))

        #pragma unroll
        for (int r = 0; r < 4; ++r) { ezc[r] = ezn[r]; erc[r] = ern[r]; ehc[r] = ehn[r]; }
    }
}

// ---------------- fallback step kernels (round-1 proven) ----------------
__global__ __launch_bounds__(256) void k_step1(
    const int* __restrict__ X,
    const float* __restrict__ Wz, const float* __restrict__ bz,
    const float* __restrict__ Wr, const float* __restrict__ br,
    const unsigned short* __restrict__ Wzh, const unsigned short* __restrict__ Wrh,
    const unsigned short* __restrict__ Hbf, const float* __restrict__ Hf,
    float* __restrict__ zbuf, unsigned short* __restrict__ rHbf, int t)
{
    int w    = threadIdx.x >> 6;
    int lane = threadIdx.x & 63;
    int nt = blockIdx.x;
    int mt = w;
    bool isz = nt < 64;
    const unsigned short* W = isz ? Wzh : Wrh;
    int ntl = nt & 63;
    int row = lane & 15;
    int kq  = (lane >> 4) << 3;
    const unsigned short* aptr = Hbf + (size_t)(mt * 16 + row) * HIDDEN + kq;
    const unsigned short* bptr = W   + (size_t)(ntl * 16 + row) * HIDDEN + kq;
    f32x4 acc = {0.f, 0.f, 0.f, 0.f};
    #pragma unroll 8
    for (int kk = 0; kk < HIDDEN / 32; ++kk) {
        short8 a = *(const short8*)(aptr + kk * 32);
        short8 b = *(const short8*)(bptr + kk * 32);
        acc = __builtin_amdgcn_mfma_f32_16x16x32_bf16(a, b, acc, 0, 0, 0);
    }
    int j = ntl * 16 + row;
    const float* Wemb = isz ? Wz : Wr;
    float bias = isz ? bz[j] : br[j];
    #pragma unroll
    for (int r = 0; r < 4; ++r) {
        int b = mt * 16 + ((lane >> 4) << 2) + r;
        int tok = X[b * SEQ + t];
        float pre = acc[r] + Wemb[(size_t)tok * HIDDEN + j] + bias;
        float s = 1.f / (1.f + expf(-pre));
        if (isz) zbuf[b * HIDDEN + j] = s;
        else     rHbf[b * HIDDEN + j] = f2bf(s * Hf[b * HIDDEN + j]);
    }
}

__global__ __launch_bounds__(256) void k_step2(
    const int* __restrict__ X,
    const float* __restrict__ Wh, const float* __restrict__ bh,
    const unsigned short* __restrict__ Whh,
    const unsigned short* __restrict__ rHbf,
    const float* __restrict__ zbuf,
    float* __restrict__ Hf, unsigned short* __restrict__ Hbf,
    unsigned short* __restrict__ Hhist, int t)
{
    int w    = threadIdx.x >> 6;
    int lane = threadIdx.x & 63;
    int nt = blockIdx.x;
    int mt = w;
    int row = lane & 15;
    int kq  = (lane >> 4) << 3;
    const unsigned short* aptr = rHbf + (size_t)(mt * 16 + row) * HIDDEN + kq;
    const unsigned short* bptr = Whh  + (size_t)(nt * 16 + row) * HIDDEN + kq;
    f32x4 acc = {0.f, 0.f, 0.f, 0.f};
    #pragma unroll 8
    for (int kk = 0; kk < HIDDEN / 32; ++kk) {
        short8 a = *(const short8*)(aptr + kk * 32);
        short8 b = *(const short8*)(bptr + kk * 32);
        acc = __builtin_amdgcn_mfma_f32_16x16x32_bf16(a, b, acc, 0, 0, 0);
    }
    int j = nt * 16 + row;
    float bias = bh[j];
    #pragma unroll
    for (int r = 0; r < 4; ++r) {
        int b = mt * 16 + ((lane >> 4) << 2) + r;
        int tok = X[b * SEQ + t];
        float pre = acc[r] + Wh[(size_t)tok * HIDDEN + j] + bias;
        float h = tanhf(pre);
        float z = zbuf[b * HIDDEN + j];
        float Hold = Hf[b * HIDDEN + j];
        float Hn = z * h + (1.f - z) * Hold;
        Hf[b * HIDDEN + j] = Hn;
        unsigned short bf = f2bf(Hn);
        Hbf[b * HIDDEN + j] = bf;
        Hhist[(size_t)t * (BATCH * HIDDEN) + b * HIDDEN + j] = bf;
    }
}

// ---------------- output projection ----------------
__global__ __launch_bounds__(256) void k_out(
    const unsigned short* __restrict__ A,
    const unsigned short* __restrict__ B,
    const float* __restrict__ bo,
    float* __restrict__ out)
{
    __shared__ __align__(16) unsigned short As[128 * 32];
    __shared__ __align__(16) unsigned short Bs[128 * 32];
    int bn = blockIdx.x & 31;
    int bm = blockIdx.x >> 5;
    int m0 = bm << 7, n0 = bn << 7;
    int tid  = threadIdx.x;
    int w    = tid >> 6, lane = tid & 63;
    int wm = w & 1, wn = w >> 1;
    int row = lane & 15;
    int kq  = (lane >> 4) << 3;

    f32x4 acc[4][4];
    #pragma unroll
    for (int i = 0; i < 4; ++i)
        #pragma unroll
        for (int jj = 0; jj < 4; ++jj)
            acc[i][jj] = (f32x4){0.f, 0.f, 0.f, 0.f};

    for (int k0 = 0; k0 < HIDDEN; k0 += 32) {
        #pragma unroll
        for (int c = 0; c < 2; ++c) {
            int off  = tid * 32 + c * 16;
            int rowi = off >> 6;
            int us   = (off & 63) >> 1;
            *(short8*)&As[rowi * 32 + us] =
                *(const short8*)&A[(size_t)(m0 + rowi) * HIDDEN + k0 + us];
            *(short8*)&Bs[rowi * 32 + us] =
                *(const short8*)&B[(size_t)(n0 + rowi) * HIDDEN + k0 + us];
        }
        __syncthreads();
        short8 a[4], b[4];
        #pragma unroll
        for (int i = 0; i < 4; ++i)
            a[i] = *(const short8*)&As[(wm * 64 + i * 16 + row) * 32 + kq];
        #pragma unroll
        for (int jj = 0; jj < 4; ++jj)
            b[jj] = *(const short8*)&Bs[(wn * 64 + jj * 16 + row) * 32 + kq];
        #pragma unroll
        for (int i = 0; i < 4; ++i)
            #pragma unroll
            for (int jj = 0; jj < 4; ++jj)
                acc[i][jj] = __builtin_amdgcn_mfma_f32_16x16x32_bf16(a[i], b[jj], acc[i][jj], 0, 0, 0);
        __syncthreads();
    }

    #pragma unroll
    for (int i = 0; i < 4; ++i) {
        #pragma unroll
        for (int jj = 0; jj < 4; ++jj) {
            int n = n0 + wn * 64 + jj * 16 + row;
            float bb = bo[n];
            #pragma unroll
            for (int r = 0; r < 4; ++r) {
                int m = m0 + wm * 64 + i * 16 + ((lane >> 4) << 2) + r;
                out[(size_t)m * VOCAB + n] = acc[i][jj][r] + bb;
            }
        }
    }
}

// ---------------- H_final copy ----------------
__global__ __launch_bounds__(256) void k_copyH(const float* __restrict__ Hf,
                                               float* __restrict__ out) {
    int i = blockIdx.x * 256 + threadIdx.x;
    if (i < BATCH * HIDDEN)
        out[(size_t)SEQ * BATCH * VOCAB + i] = Hf[i];
}

extern "C" void kernel_launch(void* const* d_in, const int* in_sizes, int n_in,
                              void* d_out, int out_size, void* d_ws, size_t ws_size,
                              hipStream_t stream) {
    const int*   X  = (const int*)  d_in[0];
    const float* Wz = (const float*)d_in[1];
    const float* bz = (const float*)d_in[2];
    const float* Wr = (const float*)d_in[3];
    const float* br = (const float*)d_in[4];
    const float* Wh = (const float*)d_in[5];
    const float* bh = (const float*)d_in[6];
    const float* Wo = (const float*)d_in[7];
    const float* bo = (const float*)d_in[8];
    float* out = (float*)d_out;
    char* ws = (char*)d_ws;

    float*          Hf    = (float*)(ws);                           // 256KB
    float*          zbuf  = (float*)(ws + (256 << 10));             // 256KB (fallback only)
    int*            flags = (int*)(ws + (512 << 10));               // 8KB
    unsigned short* Hbf   = (unsigned short*)(ws + (528 << 10));    // 128KB
    unsigned short* rHbf  = (unsigned short*)(ws + (656 << 10));    // 128KB
    unsigned short* Wzh   = (unsigned short*)(ws + (1 << 20));      // 2MB
    unsigned short* Wrh   = Wzh + 1024 * 1024;                      // 2MB
    unsigned short* Whh   = Wrh + 1024 * 1024;                      // 2MB
    unsigned short* WoT   = Whh + 1024 * 1024;                      // 8MB
    unsigned short* Hhist = WoT + (size_t)VOCAB * HIDDEN;           // 32MB

    k_zero<<<256, 256, 0, stream>>>(Hf, Hbf, flags);
    k_pack<<<32 * 32,  256, 0, stream>>>(Wz + (size_t)VOCAB * HIDDEN, Wzh, 1024, 1024);
    k_pack<<<32 * 32,  256, 0, stream>>>(Wr + (size_t)VOCAB * HIDDEN, Wrh, 1024, 1024);
    k_pack<<<32 * 32,  256, 0, stream>>>(Wh + (size_t)VOCAB * HIDDEN, Whh, 1024, 1024);
    k_pack<<<32 * 128, 256, 0, stream>>>(Wo, WoT, 1024, 4096);

    void* args[] = {
        (void*)&X, (void*)&Wz, (void*)&bz, (void*)&Wr, (void*)&br,
        (void*)&Wh, (void*)&bh, (void*)&Wzh, (void*)&Wrh, (void*)&Whh,
        (void*)&Hf, (void*)&Hbf, (void*)&rHbf, (void*)&Hhist, (void*)&flags
    };
    hipError_t cerr = hipLaunchCooperativeKernel((void*)k_scan, dim3(NWG), dim3(256),
                                                 args, 0, stream);
    if (cerr != hipSuccess) {
        for (int t = 0; t < SEQ; ++t) {
            k_step1<<<128, 256, 0, stream>>>(X, Wz, bz, Wr, br, Wzh, Wrh, Hbf, Hf, zbuf, rHbf, t);
            k_step2<<<64,  256, 0, stream>>>(X, Wh, bh, Whh, rHbf, zbuf, Hf, Hbf, Hhist, t);
        }
    }

    k_out<<<4096, 256, 0, stream>>>(Hhist, WoT, bo, out);
    k_copyH<<<256, 256, 0, stream>>>(Hf, out);
}

// Round 14
// 3178.396 us; speedup vs baseline: 1.8057x; 1.1196x over previous
//
#include <hip/hip_runtime.h>
#include <hip/hip_bf16.h>
#include <cstdint>
#include <cstddef>

#define VOCAB  4096
#define HIDDEN 1024
#define BATCH  64
#define SEQ    256
#define NWG    256      // 4 scans x 64 col-groups; 64 threads (1 wave) each
#define SCANS  4

typedef __attribute__((ext_vector_type(8))) short short8;
typedef __attribute__((ext_vector_type(4))) float f32x4;

__device__ __forceinline__ unsigned short f2bf(float f) {
    union { float f; uint32_t u; } v; v.f = f;
    uint32_t u = v.u;
    u += 0x7FFFu + ((u >> 16) & 1u);   // round-to-nearest-even
    return (unsigned short)(u >> 16);
}

// device-scope (agent) relaxed atomic store — uncached at LLC (proven r4-r13)
__device__ __forceinline__ void ast16(unsigned short* p, unsigned short v) {
    __hip_atomic_store(p, v, __ATOMIC_RELAXED, __HIP_MEMORY_SCOPE_AGENT);
}

// coherent 16B load: bypasses L1/L2 (sc0 sc1), order-pinned volatile asm (proven r7)
__device__ __forceinline__ short8 cld16(const unsigned short* p) {
    short8 v;
    asm volatile("global_load_dwordx4 %0, %1, off sc0 sc1"
                 : "=v"(v) : "v"(p) : "memory");
    return v;
}

// ---------------- zero init H + barrier flags ----------------
__global__ __launch_bounds__(256) void k_zero(float* Hf, unsigned short* Hbf, int* flags) {
    int i = blockIdx.x * 256 + threadIdx.x;
    if (i < BATCH * HIDDEN) { Hf[i] = 0.f; Hbf[i] = 0; }
    if (i < 2048) flags[i] = 0;
}

// ---------------- transpose+pack: src f32 [R][C] -> dst bf16 [C][R] ----------------
__global__ __launch_bounds__(256) void k_pack(const float* __restrict__ src,
                                              unsigned short* __restrict__ dst,
                                              int R, int C) {
    __shared__ float tile[32][33];
    int tilesC = C >> 5;
    int bx = blockIdx.x % tilesC;
    int by = blockIdx.x / tilesC;
    int tx = threadIdx.x & 31;
    int ty = threadIdx.x >> 5;
    int c0 = bx << 5, r0 = by << 5;
    #pragma unroll
    for (int s = 0; s < 4; ++s) {
        int r = ty + s * 8;
        tile[r][tx] = src[(size_t)(r0 + r) * C + (c0 + tx)];
    }
    __syncthreads();
    #pragma unroll
    for (int s = 0; s < 4; ++s) {
        int cc = ty + s * 8;
        dst[(size_t)(c0 + cc) * R + (r0 + tx)] = f2bf(tile[tx][cc]);
    }
}

// ---------------- per-scan barrier (single-wave WG: no syncthreads needed) ----------------
// lane l polls flags[scan*64 + l]; divergent exits reconverge when all 64 flags pass.
__device__ __forceinline__ void scan_barrier(int* flags, int base, int cg, int p) {
    asm volatile("s_waitcnt vmcnt(0)" ::: "memory");   // this wave's stores at LLC
    if (threadIdx.x == 0)
        __hip_atomic_store(&flags[base + cg], p, __ATOMIC_RELAXED, __HIP_MEMORY_SCOPE_AGENT);
    int l = threadIdx.x & 63;
    while (__hip_atomic_load(&flags[base + l], __ATOMIC_RELAXED, __HIP_MEMORY_SCOPE_AGENT) < p)
        __builtin_amdgcn_s_sleep(1);
    __builtin_amdgcn_sched_barrier(0);   // rule #18
}

// ---------------- persistent GRU scan: 4 independent batch-sliced scans ----------------
// WG g: scan s = g>>6 (batch rows [16s,16s+16)), col-group cg = g&63 (cols [16cg,16cg+16)).
// 64 threads (1 wave). All 3 weight slices in LDS (96KB). Exchange via uncached LLC ops.
// Scans are mutually unsynchronized -> their memory phases interleave, filling latency bubbles.
__global__ __launch_bounds__(64, 1) void k_scan(
    const int* __restrict__ X,
    const float* __restrict__ Wz, const float* __restrict__ bz,
    const float* __restrict__ Wr, const float* __restrict__ br,
    const float* __restrict__ Wh, const float* __restrict__ bh,
    const unsigned short* __restrict__ Wzh, const unsigned short* __restrict__ Wrh,
    const unsigned short* __restrict__ Whh,
    float* __restrict__ Hf, unsigned short* __restrict__ Hbf,
    unsigned short* __restrict__ rHbf, unsigned short* __restrict__ Hhist,
    int* __restrict__ flags)
{
    __shared__ __align__(16) unsigned short WzL[16 * 1024];   // 32KB
    __shared__ __align__(16) unsigned short WrL[16 * 1024];   // 32KB
    __shared__ __align__(16) unsigned short WhL[16 * 1024];   // 32KB

    const int tid  = threadIdx.x;       // 0..63 (one wave)
    const int g    = blockIdx.x;
    const int scan = g >> 6;            // 0..3
    const int cg   = g & 63;            // col group
    const int lane = tid & 63;
    const int row  = lane & 15;
    const int q    = lane >> 4;
    const int kq   = q << 3;
    const int col0 = cg << 4;
    const int j    = col0 + row;
    const int b0   = scan << 4;         // scan's batch base
    const int bq   = b0 + (q << 2);
    const int fbase = scan << 6;        // 64 flags per scan

    // ---- stage weight slices (16 cols x 3 gates) into LDS ----
    #pragma unroll
    for (int c = 0; c < 32; ++c) {
        int idx = tid + c * 64;          // 0..2047 16B chunks
        int kkg = idx >> 6;
        int rem = idx & 63;
        int qq  = rem >> 4;
        int rr  = rem & 15;
        size_t so = (size_t)(col0 + rr) * HIDDEN + kkg * 32 + qq * 8;
        *(short8*)&WzL[idx * 8] = *(const short8*)&Wzh[so];
        *(short8*)&WrL[idx * 8] = *(const short8*)&Wrh[so];
        *(short8*)&WhL[idx * 8] = *(const short8*)&Whh[so];
    }
    __syncthreads();

    const float bzj = bz[j], brj = br[j], bhj = bh[j];

    float zreg[4] = {0.f, 0.f, 0.f, 0.f};
    float Hreg[4] = {0.f, 0.f, 0.f, 0.f};
    int p = 0;

    // ---- prologue: tokens + embeddings for t=0 ----
    float ezc[4], erc[4], ehc[4];
    {
        int tk[4];
        #pragma unroll
        for (int r = 0; r < 4; ++r) tk[r] = X[(bq + r) * SEQ + 0];
        #pragma unroll
        for (int r = 0; r < 4; ++r) {
            ezc[r] = Wz[(size_t)tk[r] * HIDDEN + j];
            erc[r] = Wr[(size_t)tk[r] * HIDDEN + j];
            ehc[r] = Wh[(size_t)tk[r] * HIDDEN + j];
        }
    }

    for (int t = 0; t < SEQ; ++t) {
        const int tn = (t + 1 < SEQ) ? t + 1 : t;   // clamped: constant load counts
        int tokn[4];
        float ezn[4], ern[4], ehn[4];

        // ---------------- phase 1: z and r ----------------
        {
            const unsigned short* ap = Hbf + (size_t)(b0 + row) * HIDDEN + kq;
            short8 A[32];
            #pragma unroll
            for (int kk = 0; kk < 32; ++kk)
                A[kk] = cld16(ap + kk * 32);
            #pragma unroll
            for (int r = 0; r < 4; ++r) {
                const int* px = X + (bq + r) * SEQ + tn;
                asm volatile("global_load_dword %0, %1, off" : "=v"(tokn[r]) : "v"(px) : "memory");
            }

            f32x4 accZ = {0.f, 0.f, 0.f, 0.f}, accR = {0.f, 0.f, 0.f, 0.f};
            asm volatile("s_waitcnt vmcnt(20)" ::: "memory");   // 36-20=16: A[0..15] retired
            __builtin_amdgcn_sched_barrier(0);
            #pragma unroll
            for (int kk = 0; kk < 16; ++kk) {
                int lo = kk * 512 + q * 128 + row * 8;
                short8 fz = *(const short8*)&WzL[lo];
                short8 fr = *(const short8*)&WrL[lo];
                accZ = __builtin_amdgcn_mfma_f32_16x16x32_bf16(A[kk], fz, accZ, 0, 0, 0);
                accR = __builtin_amdgcn_mfma_f32_16x16x32_bf16(A[kk], fr, accR, 0, 0, 0);
            }
            asm volatile("s_waitcnt vmcnt(4)" ::: "memory");    // all A retired; tokens fly
            __builtin_amdgcn_sched_barrier(0);
            #pragma unroll
            for (int kk = 16; kk < 32; ++kk) {
                int lo = kk * 512 + q * 128 + row * 8;
                short8 fz = *(const short8*)&WzL[lo];
                short8 fr = *(const short8*)&WrL[lo];
                accZ = __builtin_amdgcn_mfma_f32_16x16x32_bf16(A[kk], fz, accZ, 0, 0, 0);
                accR = __builtin_amdgcn_mfma_f32_16x16x32_bf16(A[kk], fr, accR, 0, 0, 0);
            }
            // r first: its stores gate the barrier
            #pragma unroll
            for (int r = 0; r < 4; ++r) {
                float rv = 1.f / (1.f + expf(-(accR[r] + erc[r] + brj)));
                ast16(&rHbf[(bq + r) * HIDDEN + j], f2bf(rv * Hreg[r]));
            }
            #pragma unroll
            for (int r = 0; r < 4; ++r)
                zreg[r] = 1.f / (1.f + expf(-(accZ[r] + ezc[r] + bzj)));
        }

        scan_barrier(flags, fbase, cg, ++p);   // tokens retired inside (vmcnt(0))

        // ---------------- phase 2: h + state update ----------------
        {
            const unsigned short* ap = rHbf + (size_t)(b0 + row) * HIDDEN + kq;
            short8 A[32];
            #pragma unroll
            for (int kk = 0; kk < 32; ++kk)
                A[kk] = cld16(ap + kk * 32);
            // 12 embedding gathers for t+1: fly under MFMA + epilogue + store drain
            #pragma unroll
            for (int r = 0; r < 4; ++r) {
                const float* pz = Wz + (size_t)tokn[r] * HIDDEN + j;
                const float* pr = Wr + (size_t)tokn[r] * HIDDEN + j;
                const float* pm = Wh + (size_t)tokn[r] * HIDDEN + j;
                asm volatile("global_load_dword %0, %1, off" : "=v"(ezn[r]) : "v"(pz) : "memory");
                asm volatile("global_load_dword %0, %1, off" : "=v"(ern[r]) : "v"(pr) : "memory");
                asm volatile("global_load_dword %0, %1, off" : "=v"(ehn[r]) : "v"(pm) : "memory");
            }

            f32x4 accA = {0.f, 0.f, 0.f, 0.f}, accB = {0.f, 0.f, 0.f, 0.f};
            asm volatile("s_waitcnt vmcnt(28)" ::: "memory");   // 44-28=16: A[0..15] retired
            __builtin_amdgcn_sched_barrier(0);
            #pragma unroll
            for (int kk = 0; kk < 16; ++kk) {
                int lo = kk * 512 + q * 128 + row * 8;
                short8 fh = *(const short8*)&WhL[lo];
                if (kk & 1) accB = __builtin_amdgcn_mfma_f32_16x16x32_bf16(A[kk], fh, accB, 0, 0, 0);
                else        accA = __builtin_amdgcn_mfma_f32_16x16x32_bf16(A[kk], fh, accA, 0, 0, 0);
            }
            asm volatile("s_waitcnt vmcnt(12)" ::: "memory");   // all A retired; gathers fly
            __builtin_amdgcn_sched_barrier(0);
            #pragma unroll
            for (int kk = 16; kk < 32; ++kk) {
                int lo = kk * 512 + q * 128 + row * 8;
                short8 fh = *(const short8*)&WhL[lo];
                if (kk & 1) accB = __builtin_amdgcn_mfma_f32_16x16x32_bf16(A[kk], fh, accB, 0, 0, 0);
                else        accA = __builtin_amdgcn_mfma_f32_16x16x32_bf16(A[kk], fh, accA, 0, 0, 0);
            }
            #pragma unroll
            for (int r = 0; r < 4; ++r) {
                int b = bq + r;
                float h  = tanhf(accA[r] + accB[r] + ehc[r] + bhj);
                float Hn = zreg[r] * h + (1.f - zreg[r]) * Hreg[r];
                Hreg[r] = Hn;
                unsigned short bfv = f2bf(Hn);
                ast16(&Hbf[b * HIDDEN + j], bfv);
                Hhist[(size_t)t * (BATCH * HIDDEN) + b * HIDDEN + j] = bfv;
                if (t == SEQ - 1) Hf[b * HIDDEN + j] = Hn;
            }
        }

        scan_barrier(flags, fbase, cg, ++p);   // gathers retired inside (vmcnt(0))

        #pragma unroll
        for (int r = 0; r < 4; ++r) { ezc[r] = ezn[r]; erc[r] = ern[r]; ehc[r] = ehn[r]; }
    }
}

// ---------------- fallback step kernels (round-1 proven) ----------------
__global__ __launch_bounds__(256) void k_step1(
    const int* __restrict__ X,
    const float* __restrict__ Wz, const float* __restrict__ bz,
    const float* __restrict__ Wr, const float* __restrict__ br,
    const unsigned short* __restrict__ Wzh, const unsigned short* __restrict__ Wrh,
    const unsigned short* __restrict__ Hbf, const float* __restrict__ Hf,
    float* __restrict__ zbuf, unsigned short* __restrict__ rHbf, int t)
{
    int w    = threadIdx.x >> 6;
    int lane = threadIdx.x & 63;
    int nt = blockIdx.x;
    int mt = w;
    bool isz = nt < 64;
    const unsigned short* W = isz ? Wzh : Wrh;
    int ntl = nt & 63;
    int row = lane & 15;
    int kq  = (lane >> 4) << 3;
    const unsigned short* aptr = Hbf + (size_t)(mt * 16 + row) * HIDDEN + kq;
    const unsigned short* bptr = W   + (size_t)(ntl * 16 + row) * HIDDEN + kq;
    f32x4 acc = {0.f, 0.f, 0.f, 0.f};
    #pragma unroll 8
    for (int kk = 0; kk < HIDDEN / 32; ++kk) {
        short8 a = *(const short8*)(aptr + kk * 32);
        short8 b = *(const short8*)(bptr + kk * 32);
        acc = __builtin_amdgcn_mfma_f32_16x16x32_bf16(a, b, acc, 0, 0, 0);
    }
    int j = ntl * 16 + row;
    const float* Wemb = isz ? Wz : Wr;
    float bias = isz ? bz[j] : br[j];
    #pragma unroll
    for (int r = 0; r < 4; ++r) {
        int b = mt * 16 + ((lane >> 4) << 2) + r;
        int tok = X[b * SEQ + t];
        float pre = acc[r] + Wemb[(size_t)tok * HIDDEN + j] + bias;
        float s = 1.f / (1.f + expf(-pre));
        if (isz) zbuf[b * HIDDEN + j] = s;
        else     rHbf[b * HIDDEN + j] = f2bf(s * Hf[b * HIDDEN + j]);
    }
}

__global__ __launch_bounds__(256) void k_step2(
    const int* __restrict__ X,
    const float* __restrict__ Wh, const float* __restrict__ bh,
    const unsigned short* __restrict__ Whh,
    const unsigned short* __restrict__ rHbf,
    const float* __restrict__ zbuf,
    float* __restrict__ Hf, unsigned short* __restrict__ Hbf,
    unsigned short* __restrict__ Hhist, int t)
{
    int w    = threadIdx.x >> 6;
    int lane = threadIdx.x & 63;
    int nt = blockIdx.x;
    int mt = w;
    int row = lane & 15;
    int kq  = (lane >> 4) << 3;
    const unsigned short* aptr = rHbf + (size_t)(mt * 16 + row) * HIDDEN + kq;
    const unsigned short* bptr = Whh  + (size_t)(nt * 16 + row) * HIDDEN + kq;
    f32x4 acc = {0.f, 0.f, 0.f, 0.f};
    #pragma unroll 8
    for (int kk = 0; kk < HIDDEN / 32; ++kk) {
        short8 a = *(const short8*)(aptr + kk * 32);
        short8 b = *(const short8*)(bptr + kk * 32);
        acc = __builtin_amdgcn_mfma_f32_16x16x32_bf16(a, b, acc, 0, 0, 0);
    }
    int j = nt * 16 + row;
    float bias = bh[j];
    #pragma unroll
    for (int r = 0; r < 4; ++r) {
        int b = mt * 16 + ((lane >> 4) << 2) + r;
        int tok = X[b * SEQ + t];
        float pre = acc[r] + Wh[(size_t)tok * HIDDEN + j] + bias;
        float h = tanhf(pre);
        float z = zbuf[b * HIDDEN + j];
        float Hold = Hf[b * HIDDEN + j];
        float Hn = z * h + (1.f - z) * Hold;
        Hf[b * HIDDEN + j] = Hn;
        unsigned short bf = f2bf(Hn);
        Hbf[b * HIDDEN + j] = bf;
        Hhist[(size_t)t * (BATCH * HIDDEN) + b * HIDDEN + j] = bf;
    }
}

// ---------------- output projection ----------------
__global__ __launch_bounds__(256) void k_out(
    const unsigned short* __restrict__ A,
    const unsigned short* __restrict__ B,
    const float* __restrict__ bo,
    float* __restrict__ out)
{
    __shared__ __align__(16) unsigned short As[128 * 32];
    __shared__ __align__(16) unsigned short Bs[128 * 32];
    int bn = blockIdx.x & 31;
    int bm = blockIdx.x >> 5;
    int m0 = bm << 7, n0 = bn << 7;
    int tid  = threadIdx.x;
    int w    = tid >> 6, lane = tid & 63;
    int wm = w & 1, wn = w >> 1;
    int row = lane & 15;
    int kq  = (lane >> 4) << 3;

    f32x4 acc[4][4];
    #pragma unroll
    for (int i = 0; i < 4; ++i)
        #pragma unroll
        for (int jj = 0; jj < 4; ++jj)
            acc[i][jj] = (f32x4){0.f, 0.f, 0.f, 0.f};

    for (int k0 = 0; k0 < HIDDEN; k0 += 32) {
        #pragma unroll
        for (int c = 0; c < 2; ++c) {
            int off  = tid * 32 + c * 16;
            int rowi = off >> 6;
            int us   = (off & 63) >> 1;
            *(short8*)&As[rowi * 32 + us] =
                *(const short8*)&A[(size_t)(m0 + rowi) * HIDDEN + k0 + us];
            *(short8*)&Bs[rowi * 32 + us] =
                *(const short8*)&B[(size_t)(n0 + rowi) * HIDDEN + k0 + us];
        }
        __syncthreads();
        short8 a[4], b[4];
        #pragma unroll
        for (int i = 0; i < 4; ++i)
            a[i] = *(const short8*)&As[(wm * 64 + i * 16 + row) * 32 + kq];
        #pragma unroll
        for (int jj = 0; jj < 4; ++jj)
            b[jj] = *(const short8*)&Bs[(wn * 64 + jj * 16 + row) * 32 + kq];
        #pragma unroll
        for (int i = 0; i < 4; ++i)
            #pragma unroll
            for (int jj = 0; jj < 4; ++jj)
                acc[i][jj] = __builtin_amdgcn_mfma_f32_16x16x32_bf16(a[i], b[jj], acc[i][jj], 0, 0, 0);
        __syncthreads();
    }

    #pragma unroll
    for (int i = 0; i < 4; ++i) {
        #pragma unroll
        for (int jj = 0; jj < 4; ++jj) {
            int n = n0 + wn * 64 + jj * 16 + row;
            float bb = bo[n];
            #pragma unroll
            for (int r = 0; r < 4; ++r) {
                int m = m0 + wm * 64 + i * 16 + ((lane >> 4) << 2) + r;
                out[(size_t)m * VOCAB + n] = acc[i][jj][r] + bb;
            }
        }
    }
}

// ---------------- H_final copy ----------------
__global__ __launch_bounds__(256) void k_copyH(const float* __restrict__ Hf,
                                               float* __restrict__ out) {
    int i = blockIdx.x * 256 + threadIdx.x;
    if (i < BATCH * HIDDEN)
        out[(size_t)SEQ * BATCH * VOCAB + i] = Hf[i];
}

extern "C" void kernel_launch(void* const* d_in, const int* in_sizes, int n_in,
                              void* d_out, int out_size, void* d_ws, size_t ws_size,
                              hipStream_t stream) {
    const int*   X  = (const int*)  d_in[0];
    const float* Wz = (const float*)d_in[1];
    const float* bz = (const float*)d_in[2];
    const float* Wr = (const float*)d_in[3];
    const float* br = (const float*)d_in[4];
    const float* Wh = (const float*)d_in[5];
    const float* bh = (const float*)d_in[6];
    const float* Wo = (const float*)d_in[7];
    const float* bo = (const float*)d_in[8];
    float* out = (float*)d_out;
    char* ws = (char*)d_ws;

    float*          Hf    = (float*)(ws);                           // 256KB
    float*          zbuf  = (float*)(ws + (256 << 10));             // 256KB (fallback only)
    int*            flags = (int*)(ws + (512 << 10));               // 8KB
    unsigned short* Hbf   = (unsigned short*)(ws + (528 << 10));    // 128KB
    unsigned short* rHbf  = (unsigned short*)(ws + (656 << 10));    // 128KB
    unsigned short* Wzh   = (unsigned short*)(ws + (1 << 20));      // 2MB
    unsigned short* Wrh   = Wzh + 1024 * 1024;                      // 2MB
    unsigned short* Whh   = Wrh + 1024 * 1024;                      // 2MB
    unsigned short* WoT   = Whh + 1024 * 1024;                      // 8MB
    unsigned short* Hhist = WoT + (size_t)VOCAB * HIDDEN;           // 32MB

    k_zero<<<256, 256, 0, stream>>>(Hf, Hbf, flags);
    k_pack<<<32 * 32,  256, 0, stream>>>(Wz + (size_t)VOCAB * HIDDEN, Wzh, 1024, 1024);
    k_pack<<<32 * 32,  256, 0, stream>>>(Wr + (size_t)VOCAB * HIDDEN, Wrh, 1024, 1024);
    k_pack<<<32 * 32,  256, 0, stream>>>(Wh + (size_t)VOCAB * HIDDEN, Whh, 1024, 1024);
    k_pack<<<32 * 128, 256, 0, stream>>>(Wo, WoT, 1024, 4096);

    void* args[] = {
        (void*)&X, (void*)&Wz, (void*)&bz, (void*)&Wr, (void*)&br,
        (void*)&Wh, (void*)&bh, (void*)&Wzh, (void*)&Wrh, (void*)&Whh,
        (void*)&Hf, (void*)&Hbf, (void*)&rHbf, (void*)&Hhist, (void*)&flags
    };
    hipError_t cerr = hipLaunchCooperativeKernel((void*)k_scan, dim3(NWG), dim3(64),
                                                 args, 0, stream);
    if (cerr != hipSuccess) {
        for (int t = 0; t < SEQ; ++t) {
            k_step1<<<128, 256, 0, stream>>>(X, Wz, bz, Wr, br, Wzh, Wrh, Hbf, Hf, zbuf, rHbf, t);
            k_step2<<<64,  256, 0, stream>>>(X, Wh, bh, Whh, rHbf, zbuf, Hf, Hbf, Hhist, t);
        }
    }

    k_out<<<4096, 256, 0, stream>>>(Hhist, WoT, bo, out);
    k_copyH<<<256, 256, 0, stream>>>(Hf, out);
}